// Round 6
// baseline (1234.100 us; speedup 1.0000x reference)
//
#include <hip/hip_runtime.h>

#define NN 8192
#define DD 512
#define EE 262144
#define PADF 528   // padded f32 row stride (2112 B = 33 lines, odd -> full L2 set coverage)
#define SLCF 64    // gather slice width (cols): 8192*256B = 2 MiB per XCD L2 (+2 MiB headroom)

typedef __attribute__((ext_vector_type(4))) float f32x4;
typedef __attribute__((ext_vector_type(8))) short bf16x8;

__device__ inline unsigned short f2bf(float f) {
    unsigned u = __float_as_uint(f);
    u += 0x7fffu + ((u >> 16) & 1u);   // round-to-nearest-even
    return (unsigned short)(u >> 16);
}
__device__ inline float bf2f(unsigned short h) {
    unsigned u = ((unsigned)h) << 16;
    return __uint_as_float(u);
}

// ---------------- row scale: scale[r] = 1/(rowsum + 1e-4) ----------------
__global__ void rowscale_kernel(const float* __restrict__ in, int ldi, float* __restrict__ scale) {
    __shared__ float red[256];
    int r = blockIdx.x, t = threadIdx.x;
    float2 v = ((const float2*)(in + (size_t)r * ldi))[t];
    red[t] = v.x + v.y;
    __syncthreads();
    for (int st = 128; st > 0; st >>= 1) {
        if (t < st) red[t] += red[t + st];
        __syncthreads();
    }
    if (t == 0) scale[r] = 1.0f / (red[0] + 1e-4f);
}

// ---------------- final L2 normalize + cast to bf16 (reads padded y) ----------------
__global__ void l2norm_kernel(const float* __restrict__ in, unsigned short* __restrict__ emb) {
    __shared__ float red[256];
    int r = blockIdx.x, t = threadIdx.x;
    float2 v = ((const float2*)(in + (size_t)r * PADF))[t];
    red[t] = v.x * v.x + v.y * v.y;
    __syncthreads();
    for (int st = 128; st > 0; st >>= 1) {
        if (t < st) red[t] += red[t + st];
        __syncthreads();
    }
    float norm = sqrtf(red[0]);
    float scale = 1.0f / fmaxf(norm, 1e-12f);
    ushort2 o;
    o.x = f2bf(v.x * scale);
    o.y = f2bf(v.y * scale);
    ((ushort2*)(emb + (size_t)r * DD))[t] = o;
}

// ================= CSR build (once; edge_index constant across layers) ======
__global__ void hist_kernel(const int* __restrict__ ei, int* __restrict__ cnt) {
    int e = blockIdx.x * 256 + threadIdx.x;
    atomicAdd(&cnt[ei[e]], 1);
}

__global__ void scan_kernel(int* __restrict__ cnt, int* __restrict__ row_ptr) {
    __shared__ int part[256];
    int t = threadIdx.x;
    int base = t * 32;
    int local[32];
    int s = 0;
#pragma unroll
    for (int i = 0; i < 32; ++i) { local[i] = s; s += cnt[base + i]; }
    part[t] = s;
    __syncthreads();
    for (int st = 1; st < 256; st <<= 1) {
        int add = (t >= st) ? part[t - st] : 0;
        __syncthreads();
        part[t] += add;
        __syncthreads();
    }
    int offset = part[t] - s;
#pragma unroll
    for (int i = 0; i < 32; ++i) {
        row_ptr[base + i] = offset + local[i];
        cnt[base + i] = offset + local[i];
    }
    if (t == 255) row_ptr[NN] = part[255];
}

__global__ void scatter_kernel(const int* __restrict__ ei, const float* __restrict__ ew,
                               int* __restrict__ cursor, int* __restrict__ s_src,
                               float* __restrict__ s_w) {
    int e = blockIdx.x * 256 + threadIdx.x;
    int dst = ei[e];
    int pos = atomicAdd(&cursor[dst], 1);
    s_src[pos] = ei[EE + e];
    s_w[pos]   = ew[e];
}

// ---------------- split W into bf16 hi/lo (once; W shared by both layers) ----------------
__global__ void splitW_kernel(const float* __restrict__ W, unsigned short* __restrict__ Whi,
                              unsigned short* __restrict__ Wlo) {
    int i = blockIdx.x * 256 + threadIdx.x;   // float2 index
    float2 w = ((const float2*)W)[i];
    ushort2 h, l;
    h.x = f2bf(w.x); l.x = f2bf(w.x - bf2f(h.x));
    h.y = f2bf(w.y); l.y = f2bf(w.y - bf2f(h.y));
    ((ushort2*)Whi)[i] = h;
    ((ushort2*)Wlo)[i] = l;
}

// ---------------- per-edge combined weight: sw2[e] = w[e] * scale[src[e]] ----------------
__global__ void edgew_kernel(const int* __restrict__ s_src, const float* __restrict__ s_w,
                             const float* __restrict__ scale, float* __restrict__ sw2) {
    int e = blockIdx.x * 256 + threadIdx.x;
    sw2[e] = s_w[e] * scale[s_src[e]];
}

// ---------------- pad-copy x [NN][DD] -> xp [NN][PADF] ----------------
__global__ void padcopy_kernel(const float* __restrict__ in, float* __restrict__ out) {
    int i = blockIdx.x * 256 + threadIdx.x;   // f32x4 index over NN*128
    int r = i >> 7, c = i & 127;
    *(f32x4*)(out + (size_t)r * PADF + c * 4) = *(const f32x4*)(in + (size_t)r * DD + c * 4);
}

// ---------------- SpMM gather, L2-blocked by 64-col slice ----------------
// REP=1 is the production kernel (identical to previous round). REP>1 is an
// attribution probe: repeats the full edge loop REP times (same memory
// behavior per rep) so its single-dispatch duration lands in rocprof top-5.
template<int REP>
__global__ __launch_bounds__(256) void gather_spmm_bf16(const int* __restrict__ row_ptr,
                                                        const int* __restrict__ s_src,
                                                        const float* __restrict__ sw2,
                                                        const float* __restrict__ xp,
                                                        unsigned short* __restrict__ Ahi,
                                                        unsigned short* __restrict__ Alo) {
    int l = threadIdx.x & 63;
    int r = __builtin_amdgcn_readfirstlane(blockIdx.x * 4 + (threadIdx.x >> 6));
    int c0 = blockIdx.y * SLCF;
    int beg = row_ptr[r], end = row_ptr[r + 1];
    const float* xs = xp + c0 + l;
    float a0 = 0.0f, a1 = 0.0f, a2 = 0.0f, a3 = 0.0f;
    for (int rep = 0; rep < REP; ++rep) {
        int e = beg;
        for (; e + 4 <= end; e += 4) {
            int s0 = s_src[e], s1 = s_src[e + 1], s2 = s_src[e + 2], s3 = s_src[e + 3];
            float w0 = sw2[e], w1 = sw2[e + 1], w2 = sw2[e + 2], w3 = sw2[e + 3];
            float v0 = xs[(size_t)s0 * PADF];
            float v1 = xs[(size_t)s1 * PADF];
            float v2 = xs[(size_t)s2 * PADF];
            float v3 = xs[(size_t)s3 * PADF];
            a0 += w0 * v0;
            a1 += w1 * v1;
            a2 += w2 * v2;
            a3 += w3 * v3;
        }
        for (; e < end; ++e) {
            a0 += sw2[e] * xs[(size_t)s_src[e] * PADF];
        }
    }
    float o = (a0 + a2) + (a1 + a3);
    unsigned short h = f2bf(o);
    unsigned short lo = f2bf(o - bf2f(h));
    size_t oofs = (size_t)r * DD + c0 + l;
    __builtin_nontemporal_store(h,  &Ahi[oofs]);
    __builtin_nontemporal_store(lo, &Alo[oofs]);
}

// ---------------- async global->LDS helper ----------------
__device__ inline void gl_lds16(const void* g, void* l) {
    __builtin_amdgcn_global_load_lds((const __attribute__((address_space(1))) void*)g,
                                     (__attribute__((address_space(3))) void*)l, 16, 0, 0);
}

// ---------------- layer GEMM: C = elu(A @ W^T + b), bf16-split MFMA ----------------
// BM=64, BN=128, BK=64. REP>1 = attribution probe (repeats full K loop).
template<int REP>
__global__ __launch_bounds__(256, 2) void gemm_split_mfma(const unsigned short* __restrict__ Ahi,
                                                          const unsigned short* __restrict__ Alo,
                                                          const unsigned short* __restrict__ Whi,
                                                          const unsigned short* __restrict__ Wlo,
                                                          const float* __restrict__ bias,
                                                          float* __restrict__ C) {
    __shared__ unsigned short lsAh[2][64 * 32], lsAl[2][64 * 32];
    __shared__ unsigned short lsBh[2][128 * 32], lsBl[2][128 * 32];
    const int K = DD;
    int tid = threadIdx.x;
    int wave = tid >> 6, lane = tid & 63;
    int quad = lane >> 4, l16 = lane & 15;
    int lin = blockIdx.y * 128 + blockIdx.x;
    int sw  = (lin & 7) * 64 + (lin >> 3);
    int row0 = (sw & 127) * 64, col0 = (sw >> 7) * 128;
    int wm = (wave >> 1) * 32, wn = (wave & 1) * 64;

    f32x4 acc[2][4] = {};

    int ofs0 = tid * 16;
    for (int rep = 0; rep < REP; ++rep)
    for (int k0 = 0; k0 < K; k0 += 64) {
        __syncthreads();
#pragma unroll
        for (int sub = 0; sub < 2; ++sub) {
            int ks = k0 + sub * 32;
            {
                int r = ofs0 >> 6;
                int c = (ofs0 & 63) >> 1;
                size_t ga = (size_t)(row0 + r) * K + (ks + c);
                int lofs = wave * 1024;
                gl_lds16(Ahi + ga, (char*)lsAh[sub] + lofs);
                gl_lds16(Alo + ga, (char*)lsAl[sub] + lofs);
            }
#pragma unroll
            for (int rnd = 0; rnd < 2; ++rnd) {
                int ofs = rnd * 4096 + ofs0;
                int r = ofs >> 6;
                int c = (ofs & 63) >> 1;
                size_t gb = (size_t)(col0 + r) * K + (ks + c);
                int lofs = rnd * 4096 + wave * 1024;
                gl_lds16(Whi + gb, (char*)lsBh[sub] + lofs);
                gl_lds16(Wlo + gb, (char*)lsBl[sub] + lofs);
            }
        }
        __syncthreads();

#pragma unroll
        for (int sub = 0; sub < 2; ++sub) {
            bf16x8 ah[2], al[2], bh[4], bl[4];
#pragma unroll
            for (int mt = 0; mt < 2; ++mt) {
                int o = (wm + mt * 16 + l16) * 32 + quad * 8;
                ah[mt] = *(const bf16x8*)&lsAh[sub][o];
                al[mt] = *(const bf16x8*)&lsAl[sub][o];
            }
#pragma unroll
            for (int nt = 0; nt < 4; ++nt) {
                int o = (wn + nt * 16 + l16) * 32 + quad * 8;
                bh[nt] = *(const bf16x8*)&lsBh[sub][o];
                bl[nt] = *(const bf16x8*)&lsBl[sub][o];
            }
#pragma unroll
            for (int mt = 0; mt < 2; ++mt)
#pragma unroll
                for (int nt = 0; nt < 4; ++nt) {
                    acc[mt][nt] = __builtin_amdgcn_mfma_f32_16x16x32_bf16(ah[mt], bh[nt], acc[mt][nt], 0, 0, 0);
                    acc[mt][nt] = __builtin_amdgcn_mfma_f32_16x16x32_bf16(ah[mt], bl[nt], acc[mt][nt], 0, 0, 0);
                    acc[mt][nt] = __builtin_amdgcn_mfma_f32_16x16x32_bf16(al[mt], bh[nt], acc[mt][nt], 0, 0, 0);
                }
        }
    }

#pragma unroll
    for (int mt = 0; mt < 2; ++mt)
#pragma unroll
        for (int nt = 0; nt < 4; ++nt)
#pragma unroll
            for (int i = 0; i < 4; ++i) {
                int r = row0 + wm + mt * 16 + quad * 4 + i;
                int c = col0 + wn + nt * 16 + l16;
                float v = acc[mt][nt][i] + bias[c];
                C[(size_t)r * PADF + c] = v > 0.0f ? v : expm1f(v);
            }
}

// ---------------- similarity GEMM: out = relu(emb @ emb^T), bf16 MFMA ----------------
// 128x128 tile, BK=64. REP>1 = attribution probe.
template<int REP>
__global__ __launch_bounds__(256, 2) void simgemm_kernel(const unsigned short* __restrict__ A,
                                                         float* __restrict__ C) {
    __shared__ unsigned short lsA[2][128 * 32];
    __shared__ unsigned short lsB[2][128 * 32];
    const int K = DD;
    int tid = threadIdx.x;
    int wave = tid >> 6, lane = tid & 63;
    int quad = lane >> 4, l16 = lane & 15;
    int lin = blockIdx.y * 64 + blockIdx.x;
    int sw  = (lin & 7) * 512 + (lin >> 3);
    int row0 = (sw & 63) * 128, col0 = (sw >> 6) * 128;
    int wm = (wave >> 1) * 64, wn = (wave & 1) * 64;

    f32x4 acc[4][4] = {};

    int ofs0 = tid * 16;
    for (int rep = 0; rep < REP; ++rep)
    for (int k0 = 0; k0 < K; k0 += 64) {
        __syncthreads();
#pragma unroll
        for (int sub = 0; sub < 2; ++sub) {
            int ks = k0 + sub * 32;
#pragma unroll
            for (int rnd = 0; rnd < 2; ++rnd) {
                int ofs = rnd * 4096 + ofs0;
                int r = ofs >> 6;
                int c = (ofs & 63) >> 1;
                const unsigned short* ga = A + (size_t)(row0 + r) * K + (ks + c);
                const unsigned short* gb = A + (size_t)(col0 + r) * K + (ks + c);
                int lofs = rnd * 4096 + wave * 1024;
                gl_lds16(ga, (char*)lsA[sub] + lofs);
                gl_lds16(gb, (char*)lsB[sub] + lofs);
            }
        }
        __syncthreads();

#pragma unroll
        for (int sub = 0; sub < 2; ++sub) {
            bf16x8 afr[4], bfr[4];
#pragma unroll
            for (int mt = 0; mt < 4; ++mt)
                afr[mt] = *(const bf16x8*)&lsA[sub][(wm + mt * 16 + l16) * 32 + quad * 8];
#pragma unroll
            for (int nt = 0; nt < 4; ++nt)
                bfr[nt] = *(const bf16x8*)&lsB[sub][(wn + nt * 16 + l16) * 32 + quad * 8];
#pragma unroll
            for (int mt = 0; mt < 4; ++mt)
#pragma unroll
                for (int nt = 0; nt < 4; ++nt)
                    acc[mt][nt] = __builtin_amdgcn_mfma_f32_16x16x32_bf16(afr[mt], bfr[nt],
                                                                          acc[mt][nt], 0, 0, 0);
        }
    }

#pragma unroll
    for (int mt = 0; mt < 4; ++mt)
#pragma unroll
        for (int nt = 0; nt < 4; ++nt)
#pragma unroll
            for (int i = 0; i < 4; ++i) {
                int r = row0 + wm + mt * 16 + quad * 4 + i;
                int c = col0 + wn + nt * 16 + l16;
                C[(size_t)r * NN + c] = fmaxf(acc[mt][nt][i], 0.0f);
            }
}

extern "C" void kernel_launch(void* const* d_in, const int* in_sizes, int n_in,
                              void* d_out, int out_size, void* d_ws, size_t ws_size,
                              hipStream_t stream) {
    const float* x  = (const float*)d_in[0];
    const int*   ei = (const int*)d_in[1];
    const float* ew = (const float*)d_in[2];
    const float* W  = (const float*)d_in[3];
    const float* b  = (const float*)d_in[4];
    float* out = (float*)d_out;

    float* y  = (float*)d_ws;
    float* xp = y + (size_t)NN * PADF;
    unsigned short* Ahi = (unsigned short*)(xp + (size_t)NN * PADF);
    unsigned short* Alo = Ahi + (size_t)NN * DD;
    unsigned short* Whi = Alo + (size_t)NN * DD;
    unsigned short* Wlo = Whi + (size_t)DD * DD;
    float* scale  = (float*)(Wlo + (size_t)DD * DD);
    int* row_ptr  = (int*)(scale + NN);
    int* cur_cnt  = row_ptr + (NN + 1);
    int* s_src    = cur_cnt + NN;
    float* s_w    = (float*)(s_src + EE);
    float* sw2    = s_w + EE;
    unsigned short* emb = Ahi;   // Ahi dead after layer-2 gemm

    // ---- CSR build (edges identical across layers) ----
    hipMemsetAsync(cur_cnt, 0, NN * sizeof(int), stream);
    hist_kernel<<<EE / 256, 256, 0, stream>>>(ei, cur_cnt);
    scan_kernel<<<1, 256, 0, stream>>>(cur_cnt, row_ptr);
    scatter_kernel<<<EE / 256, 256, 0, stream>>>(ei, ew, cur_cnt, s_src, s_w);
    splitW_kernel<<<(DD * DD / 2) / 256, 256, 0, stream>>>(W, Whi, Wlo);
    padcopy_kernel<<<NN * (DD / 4) / 256, 256, 0, stream>>>(x, xp);

    const float* cur = x;
    int ldcur = DD;
    const float* curp = xp;
    for (int layer = 0; layer < 2; ++layer) {
        rowscale_kernel<<<NN, 256, 0, stream>>>(cur, ldcur, scale);
        edgew_kernel<<<EE / 256, 256, 0, stream>>>(s_src, s_w, scale, sw2);
        gather_spmm_bf16<1><<<dim3(NN / 4, DD / SLCF), 256, 0, stream>>>(row_ptr, s_src, sw2, curp, Ahi, Alo);
        gemm_split_mfma<1><<<dim3(NN / 64, DD / 128), 256, 0, stream>>>(Ahi, Alo, Whi, Wlo, b, y);
        cur = y; ldcur = PADF; curp = y;
    }
    l2norm_kernel<<<NN, 256, 0, stream>>>(y, emb);
    simgemm_kernel<1><<<dim3(NN / 128, NN / 128), 256, 0, stream>>>(emb, out);

    // ================= ATTRIBUTION PROBES (this round only) =================
    // Run after the real pipeline; write only dead scratch; REP chosen so each
    // probe dispatch exceeds the ~210us harness fills and lands in rocprof
    // top-5 with counters. True per-kernel cost = probe_dur / REP.
    // gemm_split probe: reads live Ahi/Alo/W (untouched), writes dead xp.
    gemm_split_mfma<16><<<dim3(NN / 64, DD / 128), 256, 0, stream>>>(
        Ahi, Alo, Whi, Wlo, b, xp);
    // gather probe: reads live y + CSR (untouched), writes dead xp region.
    gather_spmm_bf16<6><<<dim3(NN / 4, DD / SLCF), 256, 0, stream>>>(
        row_ptr, s_src, sw2, y, (unsigned short*)xp, (unsigned short*)xp + (size_t)NN * DD);
    // simgemm probe: reads intact emb, writes scratch at +64 MB (needs 268 MB).
    size_t probe_off = 64ull << 20;
    if (ws_size >= probe_off + (size_t)NN * NN * sizeof(float)) {
        float* psim = (float*)((char*)d_ws + probe_off);
        simgemm_kernel<3><<<dim3(NN / 128, NN / 128), 256, 0, stream>>>(emb, psim);
    }
}

// Round 7
// 600.770 us; speedup vs baseline: 2.0542x; 2.0542x over previous
//
#include <hip/hip_runtime.h>

#define NN 8192
#define DD 512
#define EE 262144
#define PADF 528   // padded f32 row stride (2112 B = 33 lines, odd -> full L2 set coverage)
#define SLCF 64    // gather slice width (cols): 8192*256B = 2 MiB per XCD L2

typedef __attribute__((ext_vector_type(4))) float f32x4;
typedef __attribute__((ext_vector_type(8))) short bf16x8;

__device__ inline unsigned short f2bf(float f) {
    unsigned u = __float_as_uint(f);
    u += 0x7fffu + ((u >> 16) & 1u);   // round-to-nearest-even
    return (unsigned short)(u >> 16);
}
__device__ inline float bf2f(unsigned short h) {
    unsigned u = ((unsigned)h) << 16;
    return __uint_as_float(u);
}

// ---------------- fused prep: hist | splitW | padcopy+rowscale(L1) ----------------
// blocks [0,1024): edge histogram; [1024,1536): W bf16 hi/lo split;
// [1536,3584): x pad-copy to xp + row-sum -> scale (one wave per row).
__global__ __launch_bounds__(256) void prep_kernel(const int* __restrict__ ei,
                                                   const float* __restrict__ W,
                                                   const float* __restrict__ x,
                                                   int* __restrict__ cnt,
                                                   unsigned short* __restrict__ Whi,
                                                   unsigned short* __restrict__ Wlo,
                                                   float* __restrict__ xp,
                                                   float* __restrict__ scale) {
    int b = blockIdx.x, t = threadIdx.x;
    if (b < 1024) {
        atomicAdd(&cnt[ei[b * 256 + t]], 1);
    } else if (b < 1536) {
        int i = (b - 1024) * 256 + t;       // float2 index over DD*DD/2
        float2 w = ((const float2*)W)[i];
        ushort2 h, l;
        h.x = f2bf(w.x); l.x = f2bf(w.x - bf2f(h.x));
        h.y = f2bf(w.y); l.y = f2bf(w.y - bf2f(h.y));
        ((ushort2*)Whi)[i] = h;
        ((ushort2*)Wlo)[i] = l;
    } else {
        int r = (b - 1536) * 4 + (t >> 6);
        int l = t & 63;
        f32x4 v0 = *(const f32x4*)(x + (size_t)r * DD + l * 4);
        f32x4 v1 = *(const f32x4*)(x + (size_t)r * DD + 256 + l * 4);
        *(f32x4*)(xp + (size_t)r * PADF + l * 4) = v0;
        *(f32x4*)(xp + (size_t)r * PADF + 256 + l * 4) = v1;
        float s = (v0.x + v0.y + v0.z + v0.w) + (v1.x + v1.y + v1.z + v1.w);
        for (int off = 32; off; off >>= 1) s += __shfl_xor(s, off);
        if (l == 0) scale[r] = 1.0f / (s + 1e-4f);
    }
}

__global__ void scan_kernel(int* __restrict__ cnt, int* __restrict__ row_ptr) {
    __shared__ int part[256];
    int t = threadIdx.x;
    int base = t * 32;
    int local[32];
    int s = 0;
#pragma unroll
    for (int i = 0; i < 32; ++i) { local[i] = s; s += cnt[base + i]; }
    part[t] = s;
    __syncthreads();
    for (int st = 1; st < 256; st <<= 1) {
        int add = (t >= st) ? part[t - st] : 0;
        __syncthreads();
        part[t] += add;
        __syncthreads();
    }
    int offset = part[t] - s;
#pragma unroll
    for (int i = 0; i < 32; ++i) {
        row_ptr[base + i] = offset + local[i];
        cnt[base + i] = offset + local[i];
    }
    if (t == 255) row_ptr[NN] = part[255];
}

// scatter + fused edgew(L1): sw2[pos] = w * scale[src]
__global__ void scatter_kernel(const int* __restrict__ ei, const float* __restrict__ ew,
                               const float* __restrict__ scale, int* __restrict__ cursor,
                               int* __restrict__ s_src, float* __restrict__ s_w,
                               float* __restrict__ sw2) {
    int e = blockIdx.x * 256 + threadIdx.x;
    int dst = ei[e];
    int pos = atomicAdd(&cursor[dst], 1);
    int src = ei[EE + e];
    float w = ew[e];
    s_src[pos] = src;
    s_w[pos]   = w;
    sw2[pos]   = w * scale[src];
}

// ---------------- final L2 normalize + cast to bf16 (reads padded y) ----------------
__global__ void l2norm_kernel(const float* __restrict__ in, unsigned short* __restrict__ emb) {
    __shared__ float red[256];
    int r = blockIdx.x, t = threadIdx.x;
    float2 v = ((const float2*)(in + (size_t)r * PADF))[t];
    red[t] = v.x * v.x + v.y * v.y;
    __syncthreads();
    for (int st = 128; st > 0; st >>= 1) {
        if (t < st) red[t] += red[t + st];
        __syncthreads();
    }
    float norm = sqrtf(red[0]);
    float scale = 1.0f / fmaxf(norm, 1e-12f);
    ushort2 o;
    o.x = f2bf(v.x * scale);
    o.y = f2bf(v.y * scale);
    ((ushort2*)(emb + (size_t)r * DD))[t] = o;
}

// ---------------- SpMM gather, L2-blocked by 64-col slice ----------------
// L2M=false: weights from precomputed sw2 (layer 1).
// L2M=true:  weights = s_w * (1/(rowsum[src]+1e-4)) computed in-loop (layer 2;
//            rowsum produced by gemm_split L1 epilogue -> no rowscale dispatch).
template<bool L2M>
__global__ __launch_bounds__(256) void gather_spmm_bf16(const int* __restrict__ row_ptr,
                                                        const int* __restrict__ s_src,
                                                        const float* __restrict__ sw2,
                                                        const float* __restrict__ s_w,
                                                        const float* __restrict__ rowsum,
                                                        const float* __restrict__ xp,
                                                        unsigned short* __restrict__ Ahi,
                                                        unsigned short* __restrict__ Alo) {
    int l = threadIdx.x & 63;
    int r = __builtin_amdgcn_readfirstlane(blockIdx.x * 4 + (threadIdx.x >> 6));
    int c0 = blockIdx.y * SLCF;
    int beg = row_ptr[r], end = row_ptr[r + 1];
    const float* xs = xp + c0 + l;
    float a0 = 0.0f, a1 = 0.0f, a2 = 0.0f, a3 = 0.0f;
    int e = beg;
    for (; e + 4 <= end; e += 4) {
        int s0 = s_src[e], s1 = s_src[e + 1], s2 = s_src[e + 2], s3 = s_src[e + 3];
        float w0, w1, w2, w3;
        if (L2M) {
            w0 = s_w[e]     * (1.0f / (rowsum[s0] + 1e-4f));
            w1 = s_w[e + 1] * (1.0f / (rowsum[s1] + 1e-4f));
            w2 = s_w[e + 2] * (1.0f / (rowsum[s2] + 1e-4f));
            w3 = s_w[e + 3] * (1.0f / (rowsum[s3] + 1e-4f));
        } else {
            w0 = sw2[e]; w1 = sw2[e + 1]; w2 = sw2[e + 2]; w3 = sw2[e + 3];
        }
        float v0 = xs[(size_t)s0 * PADF];
        float v1 = xs[(size_t)s1 * PADF];
        float v2 = xs[(size_t)s2 * PADF];
        float v3 = xs[(size_t)s3 * PADF];
        a0 += w0 * v0;
        a1 += w1 * v1;
        a2 += w2 * v2;
        a3 += w3 * v3;
    }
    for (; e < end; ++e) {
        int s0 = s_src[e];
        float w0 = L2M ? s_w[e] * (1.0f / (rowsum[s0] + 1e-4f)) : sw2[e];
        a0 += w0 * xs[(size_t)s0 * PADF];
    }
    float o = (a0 + a2) + (a1 + a3);
    unsigned short h = f2bf(o);
    unsigned short lo = f2bf(o - bf2f(h));
    size_t oofs = (size_t)r * DD + c0 + l;
    __builtin_nontemporal_store(h,  &Ahi[oofs]);
    __builtin_nontemporal_store(lo, &Alo[oofs]);
}

// ---------------- async global->LDS helper ----------------
__device__ inline void gl_lds16(const void* g, void* l) {
    __builtin_amdgcn_global_load_lds((const __attribute__((address_space(1))) void*)g,
                                     (__attribute__((address_space(3))) void*)l, 16, 0, 0);
}

// ---------------- layer GEMM: C = elu(A @ W^T + b), bf16-split MFMA ----------------
// BM=64, BN=128, BK=64. RS: fused next-layer row-sum (quad shfl reduce +
// one atomicAdd per row-half of the ELU output).
template<bool RS>
__global__ __launch_bounds__(256, 2) void gemm_split_mfma(const unsigned short* __restrict__ Ahi,
                                                          const unsigned short* __restrict__ Alo,
                                                          const unsigned short* __restrict__ Whi,
                                                          const unsigned short* __restrict__ Wlo,
                                                          const float* __restrict__ bias,
                                                          float* __restrict__ C,
                                                          float* __restrict__ rowsum) {
    __shared__ unsigned short lsAh[2][64 * 32], lsAl[2][64 * 32];
    __shared__ unsigned short lsBh[2][128 * 32], lsBl[2][128 * 32];
    const int K = DD;
    int tid = threadIdx.x;
    int wave = tid >> 6, lane = tid & 63;
    int quad = lane >> 4, l16 = lane & 15;
    int lin = blockIdx.y * 128 + blockIdx.x;
    int sw  = (lin & 7) * 64 + (lin >> 3);
    int row0 = (sw & 127) * 64, col0 = (sw >> 7) * 128;
    int wm = (wave >> 1) * 32, wn = (wave & 1) * 64;

    f32x4 acc[2][4] = {};

    int ofs0 = tid * 16;
    for (int k0 = 0; k0 < K; k0 += 64) {
        __syncthreads();
#pragma unroll
        for (int sub = 0; sub < 2; ++sub) {
            int ks = k0 + sub * 32;
            {
                int r = ofs0 >> 6;
                int c = (ofs0 & 63) >> 1;
                size_t ga = (size_t)(row0 + r) * K + (ks + c);
                int lofs = wave * 1024;
                gl_lds16(Ahi + ga, (char*)lsAh[sub] + lofs);
                gl_lds16(Alo + ga, (char*)lsAl[sub] + lofs);
            }
#pragma unroll
            for (int rnd = 0; rnd < 2; ++rnd) {
                int ofs = rnd * 4096 + ofs0;
                int r = ofs >> 6;
                int c = (ofs & 63) >> 1;
                size_t gb = (size_t)(col0 + r) * K + (ks + c);
                int lofs = rnd * 4096 + wave * 1024;
                gl_lds16(Whi + gb, (char*)lsBh[sub] + lofs);
                gl_lds16(Wlo + gb, (char*)lsBl[sub] + lofs);
            }
        }
        __syncthreads();

#pragma unroll
        for (int sub = 0; sub < 2; ++sub) {
            bf16x8 ah[2], al[2], bh[4], bl[4];
#pragma unroll
            for (int mt = 0; mt < 2; ++mt) {
                int o = (wm + mt * 16 + l16) * 32 + quad * 8;
                ah[mt] = *(const bf16x8*)&lsAh[sub][o];
                al[mt] = *(const bf16x8*)&lsAl[sub][o];
            }
#pragma unroll
            for (int nt = 0; nt < 4; ++nt) {
                int o = (wn + nt * 16 + l16) * 32 + quad * 8;
                bh[nt] = *(const bf16x8*)&lsBh[sub][o];
                bl[nt] = *(const bf16x8*)&lsBl[sub][o];
            }
#pragma unroll
            for (int mt = 0; mt < 2; ++mt)
#pragma unroll
                for (int nt = 0; nt < 4; ++nt) {
                    acc[mt][nt] = __builtin_amdgcn_mfma_f32_16x16x32_bf16(ah[mt], bh[nt], acc[mt][nt], 0, 0, 0);
                    acc[mt][nt] = __builtin_amdgcn_mfma_f32_16x16x32_bf16(ah[mt], bl[nt], acc[mt][nt], 0, 0, 0);
                    acc[mt][nt] = __builtin_amdgcn_mfma_f32_16x16x32_bf16(al[mt], bh[nt], acc[mt][nt], 0, 0, 0);
                }
        }
    }

    float rs[2][4];
#pragma unroll
    for (int mt = 0; mt < 2; ++mt)
#pragma unroll
        for (int i = 0; i < 4; ++i) rs[mt][i] = 0.0f;

#pragma unroll
    for (int mt = 0; mt < 2; ++mt)
#pragma unroll
        for (int nt = 0; nt < 4; ++nt)
#pragma unroll
            for (int i = 0; i < 4; ++i) {
                int r = row0 + wm + mt * 16 + quad * 4 + i;
                int c = col0 + wn + nt * 16 + l16;
                float v = acc[mt][nt][i] + bias[c];
                v = v > 0.0f ? v : expm1f(v);
                C[(size_t)r * PADF + c] = v;
                if (RS) rs[mt][i] += v;
            }

    if (RS) {
#pragma unroll
        for (int mt = 0; mt < 2; ++mt)
#pragma unroll
            for (int i = 0; i < 4; ++i) {
                float s = rs[mt][i];
                s += __shfl_xor(s, 1);
                s += __shfl_xor(s, 2);
                s += __shfl_xor(s, 4);
                s += __shfl_xor(s, 8);
                if (l16 == 0)
                    atomicAdd(&rowsum[row0 + wm + mt * 16 + quad * 4 + i], s);
            }
    }
}

// ---------------- similarity GEMM: out = relu(emb @ emb^T), bf16 MFMA ----------------
// 256x128 tile, 512 threads (8 waves, 4M x 2N, 64x64 per wave), BK=64 as two
// [*, 32] sub-tiles. LDS 48 KB -> 3 blocks/CU. Same proven 2-phase structure.
__global__ __launch_bounds__(512, 2) void simgemm_kernel(const unsigned short* __restrict__ A,
                                                         float* __restrict__ C) {
    __shared__ unsigned short lsA[2][256 * 32];   // 16 KB each
    __shared__ unsigned short lsB[2][128 * 32];   // 8 KB each
    const int K = DD;
    int tid = threadIdx.x;
    int wave = tid >> 6, lane = tid & 63;
    int quad = lane >> 4, l16 = lane & 15;
    // XCD-aware swizzle (grid 32x64 = 2048 wgs, %8==0 -> simple form bijective)
    int lin = blockIdx.y * 32 + blockIdx.x;
    int sw  = (lin & 7) * 256 + (lin >> 3);
    int row0 = (sw & 31) * 256, col0 = (sw >> 5) * 128;
    int wm = (wave & 3) * 64, wn = (wave >> 2) * 64;

    f32x4 acc[4][4] = {};

    int ofs0 = tid * 16;   // 0..8191
    for (int k0 = 0; k0 < K; k0 += 64) {
        __syncthreads();
#pragma unroll
        for (int sub = 0; sub < 2; ++sub) {
            int ks = k0 + sub * 32;
#pragma unroll
            for (int rnd = 0; rnd < 2; ++rnd) {   // A: 256x32 = 16 KB -> 2 rounds
                int ofs = rnd * 8192 + ofs0;
                int r = ofs >> 6;
                int c = (ofs & 63) >> 1;
                gl_lds16(A + (size_t)(row0 + r) * K + (ks + c),
                         (char*)lsA[sub] + rnd * 8192 + wave * 1024);
            }
            {   // B: 128x32 = 8 KB -> 1 round
                int r = ofs0 >> 6;
                int c = (ofs0 & 63) >> 1;
                gl_lds16(A + (size_t)(col0 + r) * K + (ks + c),
                         (char*)lsB[sub] + wave * 1024);
            }
        }
        __syncthreads();

#pragma unroll
        for (int sub = 0; sub < 2; ++sub) {
            bf16x8 afr[4], bfr[4];
#pragma unroll
            for (int mt = 0; mt < 4; ++mt)
                afr[mt] = *(const bf16x8*)&lsA[sub][(wm + mt * 16 + l16) * 32 + quad * 8];
#pragma unroll
            for (int nt = 0; nt < 4; ++nt)
                bfr[nt] = *(const bf16x8*)&lsB[sub][(wn + nt * 16 + l16) * 32 + quad * 8];
#pragma unroll
            for (int mt = 0; mt < 4; ++mt)
#pragma unroll
                for (int nt = 0; nt < 4; ++nt)
                    acc[mt][nt] = __builtin_amdgcn_mfma_f32_16x16x32_bf16(afr[mt], bfr[nt],
                                                                          acc[mt][nt], 0, 0, 0);
        }
    }

#pragma unroll
    for (int mt = 0; mt < 4; ++mt)
#pragma unroll
        for (int nt = 0; nt < 4; ++nt)
#pragma unroll
            for (int i = 0; i < 4; ++i) {
                int r = row0 + wm + mt * 16 + quad * 4 + i;
                int c = col0 + wn + nt * 16 + l16;
                C[(size_t)r * NN + c] = fmaxf(acc[mt][nt][i], 0.0f);
            }
}

extern "C" void kernel_launch(void* const* d_in, const int* in_sizes, int n_in,
                              void* d_out, int out_size, void* d_ws, size_t ws_size,
                              hipStream_t stream) {
    const float* x  = (const float*)d_in[0];
    const int*   ei = (const int*)d_in[1];
    const float* ew = (const float*)d_in[2];
    const float* W  = (const float*)d_in[3];
    const float* b  = (const float*)d_in[4];
    float* out = (float*)d_out;

    // workspace layout:
    // y [NN*PADF] f32 | xp [NN*PADF] f32 | Ahi [NN*DD] bf16 | Alo [NN*DD] bf16
    // | Whi,Wlo [DD*DD] bf16 | scale [NN] f32 | row_ptr [NN+1]
    // | cur_cnt [NN] | rowsum [NN] (zeroed together) | s_src [EE] | s_w [EE] | sw2 [EE]
    float* y  = (float*)d_ws;
    float* xp = y + (size_t)NN * PADF;
    unsigned short* Ahi = (unsigned short*)(xp + (size_t)NN * PADF);
    unsigned short* Alo = Ahi + (size_t)NN * DD;
    unsigned short* Whi = Alo + (size_t)NN * DD;
    unsigned short* Wlo = Whi + (size_t)DD * DD;
    float* scale  = (float*)(Wlo + (size_t)DD * DD);
    int* row_ptr  = (int*)(scale + NN);
    int* cur_cnt  = row_ptr + (NN + 1);
    float* rowsum = (float*)(cur_cnt + NN);
    int* s_src    = (int*)(rowsum + NN);
    float* s_w    = (float*)(s_src + EE);
    float* sw2    = s_w + EE;
    unsigned short* emb = Ahi;   // Ahi dead after layer-2 gemm

    // D1: zero cur_cnt + rowsum in one shot (adjacent)
    hipMemsetAsync(cur_cnt, 0, 2 * NN * sizeof(int), stream);
    // D2: hist | splitW | padcopy+rowscale(L1)
    prep_kernel<<<3584, 256, 0, stream>>>(ei, W, x, cur_cnt, Whi, Wlo, xp, scale);
    // D3: exclusive scan -> row_ptr (cur_cnt becomes cursors)
    scan_kernel<<<1, 256, 0, stream>>>(cur_cnt, row_ptr);
    // D4: scatter + fused edgew(L1)
    scatter_kernel<<<EE / 256, 256, 0, stream>>>(ei, ew, scale, cur_cnt, s_src, s_w, sw2);
    // D5-D6: layer 1
    gather_spmm_bf16<false><<<dim3(NN / 4, DD / SLCF), 256, 0, stream>>>(
        row_ptr, s_src, sw2, s_w, rowsum, xp, Ahi, Alo);
    gemm_split_mfma<true><<<dim3(NN / 64, DD / 128), 256, 0, stream>>>(
        Ahi, Alo, Whi, Wlo, b, y, rowsum);
    // D7-D8: layer 2 (gather computes 1/(rowsum+1e-4) in-loop)
    gather_spmm_bf16<true><<<dim3(NN / 4, DD / SLCF), 256, 0, stream>>>(
        row_ptr, s_src, sw2, s_w, rowsum, y, Ahi, Alo);
    gemm_split_mfma<false><<<dim3(NN / 64, DD / 128), 256, 0, stream>>>(
        Ahi, Alo, Whi, Wlo, b, y, rowsum);
    // D9-D10: normalize + similarity
    l2norm_kernel<<<NN, 256, 0, stream>>>(y, emb);
    simgemm_kernel<<<dim3(NN / 256, NN / 128), 512, 0, stream>>>(emb, out);
}